// Round 1
// baseline (14996.655 us; speedup 1.0000x reference)
//
#include <hip/hip_runtime.h>
#include <math.h>

#define BB 8
#define NN 4096
#define DD 512
#define KK 512
#define MAXIT 10

__device__ __forceinline__ float mish_f(float x) {
  float sp = (x > 20.f) ? x : log1pf(expf(x));
  return x * tanhf(sp);
}

// ---------------- transpose 512x512 (W -> Wt) ----------------
__global__ void transpose512(const float* __restrict__ W, float* __restrict__ Wt) {
  __shared__ float tile[32][33];
  int bx = blockIdx.x, by = blockIdx.y;
  int tx = threadIdx.x, ty = threadIdx.y;
  tile[ty][tx] = W[(by*32+ty)*512 + bx*32+tx];
  __syncthreads();
  Wt[(bx*32+ty)*512 + by*32+tx] = tile[tx][ty];
}

// ---------------- centers init: centers = X[:512], c2 = ||c||^2 ----------------
__global__ void init_centers(const float* __restrict__ X, float* __restrict__ centers,
                             float* __restrict__ c2) {
  int k = blockIdx.x, b = blockIdx.y, l = threadIdx.x; // 64 threads
  const float4* src = (const float4*)(X + ((size_t)b*NN + k)*DD) + l*2;
  float4* dst = (float4*)(centers + ((size_t)b*KK + k)*DD) + l*2;
  float4 a0 = src[0], a1 = src[1];
  dst[0] = a0; dst[1] = a1;
  float s = a0.x*a0.x + a0.y*a0.y + a0.z*a0.z + a0.w*a0.w
          + a1.x*a1.x + a1.y*a1.y + a1.z*a1.z + a1.w*a1.w;
  #pragma unroll
  for (int m = 32; m >= 1; m >>= 1) s += __shfl_xor(s, m);
  if (l == 0) c2[b*KK + k] = s;
}

// ---------------- GEMM core: S[i][n] = sum_k A[b][i][k] * Bmat[b][n][k] ----------------
// M = 4096 rows (grid.x*64), N = 512 cols (4 chunks of 128), K = Kd.
// EPI 0: labels = argmin_n (c2[n] - 2 S)     (k-means assignment)
// EPI 1: Gt[b][n][i] = S                     (transposed store)
// EPI 2: pooled[b][n] += sum_i mish(S + bias[n])
template<int EPI>
__global__ __launch_bounds__(256)
void gemm_bt(const float* __restrict__ A, const float* __restrict__ Bmat,
             int Kd, long long sA, long long sB,
             const float* __restrict__ c2, int* __restrict__ labels,
             float* __restrict__ Gt,
             const float* __restrict__ bias, float* __restrict__ pooled)
{
  __shared__ float Xs[64*68];
  __shared__ float Cs[128*68];
  const int t = threadIdx.x;
  const int tx = t & 31, ty = t >> 5;       // cols: tx + 32c ; rows: ty + 8r
  const int b = blockIdx.y;
  const int r0 = blockIdx.x * 64;
  const float* Ab = A + (size_t)b * sA;
  const float* Bb = Bmat + (size_t)b * sB;

  float bestd[8]; int bestk[8];
  if (EPI == 0) {
    #pragma unroll
    for (int r = 0; r < 8; ++r) { bestd[r] = 3.4e38f; bestk[r] = 0; }
  }

  for (int c0 = 0; c0 < 512; c0 += 128) {
    float acc[8][4];
    #pragma unroll
    for (int r = 0; r < 8; ++r)
      #pragma unroll
      for (int c = 0; c < 4; ++c) acc[r][c] = 0.f;

    for (int k0 = 0; k0 < Kd; k0 += 64) {
      __syncthreads();
      #pragma unroll
      for (int s = 0; s < 4; ++s) {            // stage A: 64 rows x 64 k
        int f = t + s*256;
        int row = f >> 4, k4 = f & 15;
        float4 v = *(const float4*)&Ab[(size_t)(r0+row)*Kd + k0 + 4*k4];
        *(float4*)&Xs[row*68 + 4*k4] = v;
      }
      #pragma unroll
      for (int s = 0; s < 8; ++s) {            // stage B: 128 rows x 64 k
        int f = t + s*256;
        int cl = f >> 4, k4 = f & 15;
        float4 v = *(const float4*)&Bb[(size_t)(c0+cl)*Kd + k0 + 4*k4];
        *(float4*)&Cs[cl*68 + 4*k4] = v;
      }
      __syncthreads();
      #pragma unroll 4
      for (int kk = 0; kk < 64; kk += 4) {
        float4 xv[8], cv[4];
        #pragma unroll
        for (int r = 0; r < 8; ++r) xv[r] = *(const float4*)&Xs[(ty+8*r)*68 + kk];
        #pragma unroll
        for (int c = 0; c < 4; ++c) cv[c] = *(const float4*)&Cs[(tx+32*c)*68 + kk];
        #pragma unroll
        for (int r = 0; r < 8; ++r)
          #pragma unroll
          for (int c = 0; c < 4; ++c) {
            acc[r][c] = fmaf(xv[r].x, cv[c].x, acc[r][c]);
            acc[r][c] = fmaf(xv[r].y, cv[c].y, acc[r][c]);
            acc[r][c] = fmaf(xv[r].z, cv[c].z, acc[r][c]);
            acc[r][c] = fmaf(xv[r].w, cv[c].w, acc[r][c]);
          }
      }
    }

    if (EPI == 0) {
      float c2v[4];
      #pragma unroll
      for (int c = 0; c < 4; ++c) c2v[c] = c2[b*512 + c0 + tx + 32*c];
      #pragma unroll
      for (int r = 0; r < 8; ++r)
        #pragma unroll
        for (int c = 0; c < 4; ++c) {
          float d = fmaf(-2.f, acc[r][c], c2v[c]);
          int col = c0 + tx + 32*c;
          if (d < bestd[r]) { bestd[r] = d; bestk[r] = col; }
        }
    } else if (EPI == 1) {
      __syncthreads();
      #pragma unroll
      for (int r = 0; r < 8; ++r)
        #pragma unroll
        for (int c = 0; c < 4; ++c)
          Cs[(tx+32*c)*65 + ty + 8*r] = acc[r][c];    // Ts, stride 65
      __syncthreads();
      #pragma unroll
      for (int s = 0; s < 8; ++s) {
        int f = t + s*256;
        int cl = f >> 4, r4 = f & 15;
        float4 v;
        v.x = Cs[cl*65 + 4*r4+0]; v.y = Cs[cl*65 + 4*r4+1];
        v.z = Cs[cl*65 + 4*r4+2]; v.w = Cs[cl*65 + 4*r4+3];
        *(float4*)&Gt[((size_t)b*512 + c0+cl)*4096 + r0 + 4*r4] = v;
      }
    } else {
      float rs[4];
      #pragma unroll
      for (int c = 0; c < 4; ++c) {
        float bv = bias[c0 + tx + 32*c];
        float s = 0.f;
        #pragma unroll
        for (int r = 0; r < 8; ++r) s += mish_f(acc[r][c] + bv);
        rs[c] = s;
      }
      __syncthreads();
      #pragma unroll
      for (int c = 0; c < 4; ++c) Cs[ty*128 + tx + 32*c] = rs[c];
      __syncthreads();
      if (t < 128) {
        float s = 0.f;
        #pragma unroll
        for (int g = 0; g < 8; ++g) s += Cs[g*128 + t];
        atomicAdd(&pooled[b*512 + c0 + t], s);
      }
      __syncthreads();
    }
  }

  if (EPI == 0) {
    #pragma unroll
    for (int r = 0; r < 8; ++r) {
      float d = bestd[r]; int k = bestk[r];
      #pragma unroll
      for (int m = 16; m >= 1; m >>= 1) {
        float d2 = __shfl_xor(d, m); int k2 = __shfl_xor(k, m);
        if (d2 < d || (d2 == d && k2 < k)) { d = d2; k = k2; }
      }
      if (tx == 0) labels[b*NN + r0 + ty + 8*r] = k;
    }
  }
}

// ---------------- membership lists: counts/offsets/members per batch ----------------
__global__ void build_members(const int* __restrict__ labels, int* __restrict__ counts,
                              int* __restrict__ offsets, int* __restrict__ members) {
  __shared__ int cnt[KK];
  __shared__ int scan[KK];
  __shared__ int cur[KK];
  int b = blockIdx.x, t = threadIdx.x;   // 1024 threads
  if (t < KK) cnt[t] = 0;
  __syncthreads();
  for (int i = t; i < NN; i += 1024) atomicAdd(&cnt[labels[b*NN + i]], 1);
  __syncthreads();
  if (t < KK) scan[t] = cnt[t];
  __syncthreads();
  for (int s = 1; s < KK; s <<= 1) {
    int v = 0;
    if (t < KK && t >= s) v = scan[t - s];
    __syncthreads();
    if (t < KK && t >= s) scan[t] += v;
    __syncthreads();
  }
  if (t < KK) {
    int off = scan[t] - cnt[t];
    counts[b*KK + t] = cnt[t];
    offsets[b*KK + t] = off;
    cur[t] = off;
  }
  __syncthreads();
  for (int i = t; i < NN; i += 1024) {
    int lab = labels[b*NN + i];
    int p = atomicAdd(&cur[lab], 1);
    members[b*NN + p] = i;
  }
}

// ---------------- center update: mean of member rows (+ new c2) ----------------
__global__ void update_centers(const float* __restrict__ X, const int* __restrict__ counts,
                               const int* __restrict__ offsets, const int* __restrict__ members,
                               float* __restrict__ centers, float* __restrict__ c2) {
  int k = blockIdx.x, b = blockIdx.y, l = threadIdx.x; // 64 threads
  int cnt = counts[b*KK + k];
  if (cnt == 0) return;                 // keep old center, c2 unchanged
  int off = offsets[b*KK + k];
  const float* Xb = X + (size_t)b*NN*DD;
  float4 a0 = {0,0,0,0}, a1 = {0,0,0,0};
  for (int m = 0; m < cnt; ++m) {
    int i = members[b*NN + off + m];
    const float4* r = (const float4*)(Xb + (size_t)i*DD) + l*2;
    float4 v0 = r[0], v1 = r[1];
    a0.x+=v0.x; a0.y+=v0.y; a0.z+=v0.z; a0.w+=v0.w;
    a1.x+=v1.x; a1.y+=v1.y; a1.z+=v1.z; a1.w+=v1.w;
  }
  float fc = (float)cnt;
  a0.x/=fc; a0.y/=fc; a0.z/=fc; a0.w/=fc;
  a1.x/=fc; a1.y/=fc; a1.z/=fc; a1.w/=fc;
  float4* dst = (float4*)(centers + ((size_t)b*KK + k)*DD) + l*2;
  dst[0] = a0; dst[1] = a1;
  float s = a0.x*a0.x+a0.y*a0.y+a0.z*a0.z+a0.w*a0.w
          + a1.x*a1.x+a1.y*a1.y+a1.z*a1.z+a1.w*a1.w;
  #pragma unroll
  for (int m = 32; m >= 1; m >>= 1) s += __shfl_xor(s, m);
  if (l == 0) c2[b*KK + k] = s;
}

// ---------------- h = mish(adj @ one_hot(labels)) via per-row cluster gather ----------------
__global__ void gather_mish(const float* __restrict__ adj, const int* __restrict__ counts,
                            const int* __restrict__ offsets, const int* __restrict__ members,
                            float* __restrict__ hout) {
  __shared__ float row[NN];
  int i = blockIdx.x, b = blockIdx.y, t = threadIdx.x;  // 256 threads
  const float4* ar = (const float4*)(adj + ((size_t)b*NN + i)*NN);
  #pragma unroll
  for (int s = 0; s < 4; ++s) {
    int f = t + s*256;
    *(float4*)&row[4*f] = ar[f];
  }
  __syncthreads();
  #pragma unroll
  for (int h = 0; h < 2; ++h) {
    int k = t + h*256;
    int cnt = counts[b*KK + k];
    int off = offsets[b*KK + k];
    float s = 0.f;
    for (int m = 0; m < cnt; ++m) s += row[members[b*NN + off + m]];
    hout[((size_t)b*NN + i)*DD + k] = mish_f(s);
  }
}

// ---------------- out = pooled @ Wp + bp ----------------
__global__ void final_out(const float* __restrict__ pooled, const float* __restrict__ Wp,
                          const float* __restrict__ bp, float* __restrict__ out) {
  int b = blockIdx.x, l = threadIdx.x;  // 64 threads
  float acc[10];
  #pragma unroll
  for (int o = 0; o < 10; ++o) acc[o] = 0.f;
  for (int k = l; k < 512; k += 64) {
    float p = pooled[b*512 + k];
    #pragma unroll
    for (int o = 0; o < 10; ++o) acc[o] = fmaf(p, Wp[k*10+o], acc[o]);
  }
  #pragma unroll
  for (int o = 0; o < 10; ++o) {
    float s = acc[o];
    #pragma unroll
    for (int m = 32; m >= 1; m >>= 1) s += __shfl_xor(s, m);
    if (l == 0) out[b*10+o] = s + bp[o];
  }
}

extern "C" void kernel_launch(void* const* d_in, const int* in_sizes, int n_in,
                              void* d_out, int out_size, void* d_ws, size_t ws_size,
                              hipStream_t stream) {
  const float* x    = (const float*)d_in[0];
  const float* adj  = (const float*)d_in[1];
  const float* W    = (const float*)d_in[2];
  const float* bias = (const float*)d_in[3];
  const float* Wp   = (const float*)d_in[4];
  const float* bp   = (const float*)d_in[5];
  float* out = (float*)d_out;

  char* ws = (char*)d_ws;
  size_t off = 0;
  auto alloc = [&](size_t bytes) {
    void* p = ws + off;
    off += (bytes + 255) & ~(size_t)255;
    return p;
  };
  float* hbuf    = (float*)alloc((size_t)BB*NN*DD*4);   // 64 MB
  float* Gt      = (float*)alloc((size_t)BB*DD*NN*4);   // 64 MB
  float* centers = (float*)alloc((size_t)BB*KK*DD*4);   // 8 MB
  float* c2      = (float*)alloc((size_t)BB*KK*4);
  int*   labels  = (int*)alloc((size_t)BB*NN*4);
  int*   counts  = (int*)alloc((size_t)BB*KK*4);
  int*   offsets = (int*)alloc((size_t)BB*KK*4);
  int*   members = (int*)alloc((size_t)BB*NN*4);
  float* pooled  = (float*)alloc((size_t)BB*DD*4);
  float* Wt      = (float*)alloc((size_t)DD*DD*4);      // 1 MB

  transpose512<<<dim3(16,16), dim3(32,32), 0, stream>>>(W, Wt);

  const float* Xcur = x;
  for (int layer = 0; layer < 3; ++layer) {
    init_centers<<<dim3(KK,BB), dim3(64), 0, stream>>>(Xcur, centers, c2);
    for (int it = 0; it < MAXIT; ++it) {
      gemm_bt<0><<<dim3(64,BB), dim3(256), 0, stream>>>(
          Xcur, centers, DD, (long long)NN*DD, (long long)KK*DD,
          c2, labels, nullptr, nullptr, nullptr);
      build_members<<<dim3(BB), dim3(1024), 0, stream>>>(labels, counts, offsets, members);
      if (it < MAXIT-1)
        update_centers<<<dim3(KK,BB), dim3(64), 0, stream>>>(
            Xcur, counts, offsets, members, centers, c2);
    }
    gather_mish<<<dim3(NN,BB), dim3(256), 0, stream>>>(adj, counts, offsets, members, hbuf);
    Xcur = hbuf;
  }

  // Gt = (h3 @ W)^T   (Bmat = Wt, shared across batches -> stride 0)
  gemm_bt<1><<<dim3(64,BB), dim3(256), 0, stream>>>(
      Xcur, Wt, DD, (long long)NN*DD, 0LL,
      nullptr, nullptr, Gt, nullptr, nullptr);

  hipMemsetAsync(pooled, 0, (size_t)BB*DD*4, stream);

  // pooled[b][k] = sum_i mish( (adj @ G)[i][k] + bias[k] )
  gemm_bt<2><<<dim3(64,BB), dim3(256), 0, stream>>>(
      adj, Gt, NN, (long long)NN*NN, (long long)DD*NN,
      nullptr, nullptr, nullptr, bias, pooled);

  final_out<<<dim3(BB), dim3(64), 0, stream>>>(pooled, Wp, bp, out);
}